// Round 8
// baseline (144.871 us; speedup 1.0000x reference)
//
#include <hip/hip_runtime.h>
#include <math.h>

// LinearAttention: B=2, S=4096, D=1024, H=16, Dh=64
// Round 8 (= r7 fixed): QKV GEMM -> k_gemm8: m201-style 8-phase 256x256 schedule.
// BK=64 as 2 kh-blocks; 2 dbuf = 128KB LDS; 8 waves; per phase: {ds_read 8|4,
// stage 1 half-tile (2 gload_lds), s_barrier, 16 MFMA, s_barrier}; vmcnt(4)
// checkpoints at ph4/ph8 only (2 half-tiles in flight, no drain-0 in loop).
// Out-GEMM keeps r6's k_gemm7 (3-ring counted vmcnt).

#define EPSF 1e-8f

typedef unsigned short u16;
typedef unsigned int   u32;
typedef __attribute__((ext_vector_type(8))) short short8v;
typedef __attribute__((ext_vector_type(4))) float f32x4;

__device__ __forceinline__ float elu1(float x){ return x > 0.f ? x + 1.f : __expf(x); }
__device__ __forceinline__ u16 f2bf(float f){
    union{float f; u32 i;} c; c.f = f;
    u32 i = c.i + 0x7FFFu + ((c.i >> 16) & 1u);   // RNE
    return (u16)(i >> 16);
}
__device__ __forceinline__ float bf2f(u16 v){ union{u32 i; float f;} c; c.i = (u32)v << 16; return c.f; }
__device__ __forceinline__ float bflo(u32 v){ union{u32 i; float f;} c; c.i = v << 16; return c.f; }
__device__ __forceinline__ float bfhi(u32 v){ union{u32 i; float f;} c; c.i = v & 0xffff0000u; return c.f; }
__device__ __forceinline__ void f4a(float4 v, float* a){ a[0]=v.x; a[1]=v.y; a[2]=v.z; a[3]=v.w; }

__device__ __forceinline__ void gload16(const void* g, void* l){
    __builtin_amdgcn_global_load_lds((const __attribute__((address_space(1))) u32*)g,
                                     (__attribute__((address_space(3))) u32*)l, 16, 0, 0);
}

// ---------------- Kernel 0: cast fp32 -> bf16 ----------------
__global__ __launch_bounds__(256) void k_cast5(
    const float* __restrict__ x,  const float* __restrict__ wq,
    const float* __restrict__ wk, const float* __restrict__ wv,
    const float* __restrict__ wo,
    u16* __restrict__ xb, u16* __restrict__ wcat, u16* __restrict__ wob)
{
    size_t i8 = ((size_t)blockIdx.x * 256 + threadIdx.x) * 8;
    const float* s; u16* d; size_t off;
    if      (i8 <  8388608) { s = x;  d = xb;            off = i8; }
    else if (i8 <  9437184) { s = wq; d = wcat;          off = i8 - 8388608; }
    else if (i8 < 10485760) { s = wk; d = wcat + 1048576; off = i8 - 9437184; }
    else if (i8 < 11534336) { s = wv; d = wcat + 2097152; off = i8 - 10485760; }
    else                    { s = wo; d = wob;           off = i8 - 11534336; }
    float4 a = *(const float4*)&s[off];
    float4 b = *(const float4*)&s[off + 4];
    uint4 p;
    p.x = (u32)f2bf(a.x) | ((u32)f2bf(a.y) << 16);
    p.y = (u32)f2bf(a.z) | ((u32)f2bf(a.w) << 16);
    p.z = (u32)f2bf(b.x) | ((u32)f2bf(b.y) << 16);
    p.w = (u32)f2bf(b.z) | ((u32)f2bf(b.w) << 16);
    *(uint4*)&d[off] = p;
}

// ---------------- k_gemm8: 8-phase 256x256 fused QKV GEMM ----------------
// C[8192][3x1024] = A[8192][1024] * Wcat[3072][1024]^T. 512 thr, 8 waves (2m x 4n),
// wave tile 128x64 (acc[8][4]). LDS regions: A0=0 B0=32K A1=64K B1=96K; each region
// = [2 kh][128 lines x 128B], swizzle slot = ((row&1)*4+kg)^(line&7) (0-conflict,
// proven r4-r6). Half-tile = one kh block (16KB contiguous) -> stageable linear.
// Phases per iter j (tiles t=2j->dbuf0, t+1->dbuf1), quadrant=(mh,kk):
//  ph1 (d0,mh0,kk0) stage A1.kh1<-t+1 | ph2 (d0,mh1,kk0) stage B1.kh1<-t+1
//  ph3 (d0,mh0,kk1) stage A0.kh0<-t+2 | ph4 (d0,mh1,kk1) stage B0.kh0<-t+2, vmcnt(4)
//  ph5 (d1,mh0,kk0) stage A0.kh1<-t+2 | ph6 (d1,mh1,kk0) stage B0.kh1<-t+2
//  ph7 (d1,mh0,kk1) stage A1.kh0<-t+3 | ph8 (d1,mh1,kk1) stage B1.kh0<-t+3, vmcnt(4)
// Clobber: each staged region's last reader is a strictly earlier phase; the
// double barrier makes stage-issue-after-last-reader race-free. Landing: each
// read's source stage is >=2 checkpoints old => guaranteed by vmcnt(4) at
// ph4/ph8. Final iter peeled (vmcnt(0) once).
#define R_A0 0
#define R_B0 32768
#define R_A1 65536
#define R_B1 98304

#define STG8(REG, SRC, T, KH) { \
    gload16((SRC) + (size_t)(T)*64 + (KH)*32,          dsm + (REG) + (KH)*16384 + wid*1024); \
    gload16((SRC) + 131072 + (size_t)(T)*64 + (KH)*32, dsm + (REG) + (KH)*16384 + 8192 + wid*1024); }

#define PHA8(REGA, REGB, KK, STCODE) { \
    _Pragma("unroll") for (int n = 0; n < 4; ++n) \
        bfr[n] = *(const short8v*)(dsm + (REGB) + (KK)*16384 + offB0 + n*1024); \
    _Pragma("unroll") for (int m = 0; m < 4; ++m) \
        afr[m] = *(const short8v*)(dsm + (REGA) + (KK)*16384 + offA0 + m*1024); \
    STCODE; \
    asm volatile("s_barrier" ::: "memory"); \
    __builtin_amdgcn_s_setprio(1); \
    _Pragma("unroll") for (int m = 0; m < 4; ++m) \
        _Pragma("unroll") for (int n = 0; n < 4; ++n) \
            acc[m][n] = __builtin_amdgcn_mfma_f32_16x16x32_bf16(afr[m], bfr[n], acc[m][n], 0, 0, 0); \
    __builtin_amdgcn_s_setprio(0); \
    asm volatile("s_barrier" ::: "memory"); }

#define PHB8(REGA, KK, STCODE, WCODE) { \
    _Pragma("unroll") for (int m = 0; m < 4; ++m) \
        afr[m] = *(const short8v*)(dsm + (REGA) + (KK)*16384 + 4096 + offA0 + m*1024); \
    STCODE; \
    asm volatile("s_barrier" ::: "memory"); \
    __builtin_amdgcn_s_setprio(1); \
    _Pragma("unroll") for (int m = 0; m < 4; ++m) \
        _Pragma("unroll") for (int n = 0; n < 4; ++n) \
            acc[4+m][n] = __builtin_amdgcn_mfma_f32_16x16x32_bf16(afr[m], bfr[n], acc[4+m][n], 0, 0, 0); \
    __builtin_amdgcn_s_setprio(0); \
    WCODE; \
    asm volatile("s_barrier" ::: "memory"); }

__global__ __launch_bounds__(512, 2) void k_gemm8(
    const u16* __restrict__ Ag, const u16* __restrict__ Wg, u16* __restrict__ C)
{
    extern __shared__ char dsm[];
    const int bid = blockIdx.x;
    const int nid = (bid & 7) * 48 + (bid >> 3);   // 384 = 8*48 bijective XCD swizzle
    const int bx  = nid / 12;                      // m-tile 0..31
    const int by  = nid % 12;                      // n-tile 0..11 (into 3072)
    const int m0  = bx * 256;
    const int n0  = by * 256;

    const int tid = threadIdx.x;
    const int l   = tid & 63;
    const int wid = tid >> 6;       // 0..7
    const int wm  = wid >> 2;       // 0..1
    const int wn  = wid & 3;        // 0..3
    const int li  = l & 15;
    const int kgi = l >> 4;

    const int ra0 = wm*128 + li;
    const int offA0 = ((ra0 >> 1) << 7) + (((((ra0 & 1) << 2) | kgi) ^ ((ra0 >> 1) & 7)) << 4);
    const int rb0 = wn*64 + li;
    const int offB0 = ((rb0 >> 1) << 7) + (((((rb0 & 1) << 2) | kgi) ^ ((rb0 >> 1) & 7)) << 4);

    const int sx   = (l & 7) ^ (l >> 3);
    const int rowb = 2*(wid*8 + (l >> 3)) + (sx >> 2);   // 0..127
    const int skg  = (sx & 3) * 8;
    const u16* srcA = Ag + (size_t)(m0 + rowb) * 1024 + skg;
    const u16* srcB = Wg + (size_t)(n0 + rowb) * 1024 + skg;

    f32x4 acc[8][4];
    #pragma unroll
    for (int m = 0; m < 8; ++m)
        #pragma unroll
        for (int n = 0; n < 4; ++n) acc[m][n] = (f32x4){0.f, 0.f, 0.f, 0.f};

    short8v afr[4], bfr[4];

    // prologue: t0 full (dbuf0) + t1.kh0 (dbuf1); vmcnt(4) -> t0 landed
    STG8(R_A0, srcA, 0, 0); STG8(R_B0, srcB, 0, 0);
    STG8(R_A0, srcA, 0, 1); STG8(R_B0, srcB, 0, 1);
    STG8(R_A1, srcA, 1, 0); STG8(R_B1, srcB, 1, 0);
    asm volatile("s_waitcnt vmcnt(4)" ::: "memory");
    asm volatile("s_barrier" ::: "memory");

    #pragma unroll 1
    for (int j = 0; j < 7; ++j) {
        const int t = 2*j;
        PHA8(R_A0, R_B0, 0, { STG8(R_A1, srcA, t+1, 1) });
        PHB8(R_A0, 0,      { STG8(R_B1, srcB, t+1, 1) }, {});
        PHA8(R_A0, R_B0, 1, { STG8(R_A0, srcA, t+2, 0) });
        PHB8(R_A0, 1,      { STG8(R_B0, srcB, t+2, 0) },
             { asm volatile("s_waitcnt vmcnt(4)" ::: "memory"); });
        PHA8(R_A1, R_B1, 0, { STG8(R_A0, srcA, t+2, 1) });
        PHB8(R_A1, 0,      { STG8(R_B0, srcB, t+2, 1) }, {});
        PHA8(R_A1, R_B1, 1, { STG8(R_A1, srcA, t+3, 0) });
        PHB8(R_A1, 1,      { STG8(R_B1, srcB, t+3, 0) },
             { asm volatile("s_waitcnt vmcnt(4)" ::: "memory"); });
    }
    // peeled final iter (t=14): only t15.kh1 left to stage; vmcnt(0) once at ph4
    PHA8(R_A0, R_B0, 0, { STG8(R_A1, srcA, 15, 1) });
    PHB8(R_A0, 0,      { STG8(R_B1, srcB, 15, 1) }, {});
    PHA8(R_A0, R_B0, 1, {});
    PHB8(R_A0, 1, {},  { asm volatile("s_waitcnt vmcnt(0)" ::: "memory"); });
    PHA8(R_A1, R_B1, 0, {});
    PHB8(R_A1, 0, {}, {});
    PHA8(R_A1, R_B1, 1, {});
    PHB8(R_A1, 1, {}, {});

    // epilogue. C/D layout: col = lane&15, row = (lane>>4)*4 + reg
    const int matrix = by >> 2;                 // 0:Q 1:K 2:V
    const bool do_elu = matrix < 2;
    u16* outp = C + (size_t)matrix * 8388608;
    const int r0 = m0 + wm*128 + kgi*4;
    const int c0 = (by & 3)*256 + wn*64 + li;
    #pragma unroll
    for (int m = 0; m < 8; ++m)
        #pragma unroll
        for (int n = 0; n < 4; ++n)
            #pragma unroll
            for (int r = 0; r < 4; ++r) {
                float v = acc[m][n][r];
                if (do_elu) v = elu1(v);
                outp[(size_t)(r0 + m*16 + r) * 1024 + c0 + n*16] = f2bf(v);
            }
}

// ---------------- k_gemm7 (r6): out GEMM (f32 out), 3-buffer ring + counted vmcnt ----------------
template<int NBY>
__global__ __launch_bounds__(256, 2) void k_gemm7(
    const u16* __restrict__ Ag, const u16* __restrict__ Wg, float* __restrict__ Cv)
{
    __shared__ __align__(16) char dsm[73728];
    const int bid = blockIdx.x;
    const int nid = (bid & 7) * ((32 * NBY) >> 3) + (bid >> 3);
    const int bx  = nid / NBY;
    const int by  = nid % NBY;
    const int m0  = bx * 256;
    const int n0  = by * 128;

    const int tid = threadIdx.x;
    const int l   = tid & 63;
    const int wid = tid >> 6;
    const int wm  = wid >> 1;
    const int wn  = wid & 1;
    const int li  = l & 15;
    const int kgi = l >> 4;

    const int ra0 = wm*128 + li;
    const int offA0 = (ra0 >> 1)*128 + (((((ra0 & 1) << 2) | kgi) ^ ((ra0 >> 1) & 7)) << 4);
    const int rb0 = wn*64 + li;
    const int offB0 = (rb0 >> 1)*128 + (((((rb0 & 1) << 2) | kgi) ^ ((rb0 >> 1) & 7)) << 4);

    const int sx   = (l & 7) ^ (l >> 3);
    const int rowb = 2*(wid*8 + (l >> 3)) + (sx >> 2);
    const int skg  = (sx & 3) * 8;
    const u16* srcA = Ag + (size_t)(m0 + rowb) * 1024 + skg;
    const u16* srcB = Wg + (size_t)(n0 + rowb) * 1024 + skg;

    f32x4 acc[8][4];
    #pragma unroll
    for (int m = 0; m < 8; ++m)
        #pragma unroll
        for (int n = 0; n < 4; ++n) acc[m][n] = (f32x4){0.f, 0.f, 0.f, 0.f};

    #define ST7(BUF, T) { \
        char* ab = dsm + (BUF)*24576; \
        char* bb = ab + 16384; \
        _Pragma("unroll") for (int j = 0; j < 4; ++j) \
            gload16(srcA + (size_t)j*65536 + (T)*32, ab + j*4096 + wid*1024); \
        _Pragma("unroll") for (int j = 0; j < 2; ++j) \
            gload16(srcB + (size_t)j*65536 + (T)*32, bb + j*4096 + wid*1024); }

    #define CP7(BUF) { \
        const char* Ab = dsm + (BUF)*24576; \
        const char* Bb = Ab + 16384; \
        short8v bfr[4]; \
        _Pragma("unroll") for (int n = 0; n < 4; ++n) bfr[n] = *(const short8v*)(Bb + offB0 + n*1024); \
        __builtin_amdgcn_s_setprio(1); \
        _Pragma("unroll") for (int m = 0; m < 8; ++m) { \
            short8v afr = *(const short8v*)(Ab + offA0 + m*1024); \
            _Pragma("unroll") for (int n = 0; n < 4; ++n) \
                acc[m][n] = __builtin_amdgcn_mfma_f32_16x16x32_bf16(afr, bfr[n], acc[m][n], 0, 0, 0); \
        } \
        __builtin_amdgcn_s_setprio(0); }

    #define STEP7(CUR, STB, TS) { \
        ST7(STB, TS); \
        CP7(CUR); \
        asm volatile("s_waitcnt vmcnt(6)" ::: "memory"); \
        __builtin_amdgcn_s_barrier(); }

    ST7(0, 0); ST7(1, 1);
    asm volatile("s_waitcnt vmcnt(6)" ::: "memory");
    __builtin_amdgcn_s_barrier();

    #pragma unroll 1
    for (int g = 0; g < 10; ++g) {
        const int t = g * 3;
        STEP7(0, 2, t + 2);
        STEP7(1, 0, t + 3);
        STEP7(2, 1, t + 4);
    }
    CP7(0);
    asm volatile("s_waitcnt vmcnt(0)" ::: "memory");
    __builtin_amdgcn_s_barrier();
    CP7(1);
    #undef STEP7
    #undef CP7
    #undef ST7

    const int r0 = m0 + wm*128 + kgi*4;
    const int c0 = by*128 + wn*64 + li;
    #pragma unroll
    for (int m = 0; m < 8; ++m)
        #pragma unroll
        for (int n = 0; n < 4; ++n)
            #pragma unroll
            for (int r = 0; r < 4; ++r)
                Cv[(size_t)(r0 + m*16 + r) * 1024 + c0 + n*16] = acc[m][n][r];
}

// ---------------- per-chunk KV sums (bf16 in, bf16 out [e][d], fp32 accum) ----------------
__global__ __launch_bounds__(256) void k_chunksums(
    const u16* __restrict__ Kg, const u16* __restrict__ Vg,
    u16* __restrict__ CKVb, float* __restrict__ CKS)
{
    const int tid = threadIdx.x;
    const int tx = tid & 15, ty = tid >> 4;
    const int c  = blockIdx.x & 63;
    const int bh = blockIdx.x >> 6;
    const int b = bh >> 4, h = bh & 15;
    const int row0 = b * 4096 + c * 64;
    const int col  = h * 64;

    __shared__ float Ks[64][68];
    __shared__ float Vs[64][68];

    #pragma unroll
    for (int r = 0; r < 2; ++r) {
        int idx = tid + r * 256;
        int i = idx >> 3, cg = (idx & 7) << 3;
        uint4 ku = *(const uint4*)&Kg[(size_t)(row0 + i) * 1024 + col + cg];
        uint4 vu = *(const uint4*)&Vg[(size_t)(row0 + i) * 1024 + col + cg];
        Ks[i][cg+0]=bflo(ku.x); Ks[i][cg+1]=bfhi(ku.x);
        Ks[i][cg+2]=bflo(ku.y); Ks[i][cg+3]=bfhi(ku.y);
        Ks[i][cg+4]=bflo(ku.z); Ks[i][cg+5]=bfhi(ku.z);
        Ks[i][cg+6]=bflo(ku.w); Ks[i][cg+7]=bfhi(ku.w);
        Vs[i][cg+0]=bflo(vu.x); Vs[i][cg+1]=bfhi(vu.x);
        Vs[i][cg+2]=bflo(vu.y); Vs[i][cg+3]=bfhi(vu.y);
        Vs[i][cg+4]=bflo(vu.z); Vs[i][cg+5]=bfhi(vu.z);
        Vs[i][cg+6]=bflo(vu.w); Vs[i][cg+7]=bfhi(vu.w);
    }
    __syncthreads();

    float acc[4][4] = {};
    #pragma unroll 8
    for (int i = 0; i < 64; ++i) {
        float kv[4], vv[4];
        f4a(*(const float4*)&Ks[i][ty*4], kv);
        f4a(*(const float4*)&Vs[i][tx*4], vv);
        #pragma unroll
        for (int a = 0; a < 4; ++a)
            #pragma unroll
            for (int e = 0; e < 4; ++e)
                acc[a][e] = fmaf(kv[a], vv[e], acc[a][e]);
    }
    u16* ckv = &CKVb[(size_t)blockIdx.x * 4096];
    #pragma unroll
    for (int e = 0; e < 4; ++e) {
        u32 p0 = (u32)f2bf(acc[0][e]) | ((u32)f2bf(acc[1][e]) << 16);
        u32 p1 = (u32)f2bf(acc[2][e]) | ((u32)f2bf(acc[3][e]) << 16);
        *(uint2*)&ckv[(tx*4 + e) * 64 + ty*4] = make_uint2(p0, p1);
    }

    if (tid < 64) {
        float s = 0.f;
        #pragma unroll 8
        for (int i = 0; i < 64; ++i) s += Ks[i][tid];
        CKS[(size_t)blockIdx.x * 64 + tid] = s;
    }
}

// ---------------- exclusive prefix over chunks (CKV bf16 in-place + CKS fused) ----------------
__global__ __launch_bounds__(256) void k_prefix(u16* __restrict__ CKV, float* __restrict__ CKS)
{
    if (blockIdx.x < 512) {
        const int bh = blockIdx.x >> 4;
        const int p  = ((blockIdx.x & 15) << 8) + threadIdx.x;
        const size_t base = (size_t)bh * 64 * 4096 + p;
        float acc = 0.f;
        #pragma unroll
        for (int c = 0; c < 64; ++c) {
            float t = bf2f(CKV[base + (size_t)c * 4096]);
            CKV[base + (size_t)c * 4096] = f2bf(acc);
            acc += t;
        }
    } else {
        const int idx = (blockIdx.x - 512) * 256 + threadIdx.x;
        const int bh = idx >> 6, d = idx & 63;
        const size_t base = (size_t)bh * 64 * 64 + d;
        float v[64];
        #pragma unroll
        for (int c = 0; c < 64; ++c) v[c] = CKS[base + (size_t)c * 64];
        float acc = 0.f;
        #pragma unroll
        for (int c = 0; c < 64; ++c) { float t = v[c]; CKS[base + (size_t)c * 64] = acc; acc += t; }
    }
}

// ---------------- MFMA per-chunk attention ----------------
#define LSTR 72
__global__ __launch_bounds__(256) void k_attn2(
    const u16* __restrict__ Qg, const u16* __restrict__ Kg, const u16* __restrict__ Vg,
    const u16* __restrict__ Stg, const float* __restrict__ KSg, u16* __restrict__ AO)
{
    const int tid = threadIdx.x;
    const int l = tid & 63;
    const int w = tid >> 6;
    const int c  = blockIdx.x & 63;
    const int bh = blockIdx.x >> 6;
    const int row0 = (bh >> 4) * 4096 + c * 64;
    const int col  = (bh & 15) * 64;

    __shared__ __align__(16) u16 Qs [64 * LSTR];
    __shared__ __align__(16) u16 Ks [64 * LSTR];
    __shared__ __align__(16) u16 Vt [64 * LSTR];
    __shared__ __align__(16) u16 Sts[64 * LSTR];
    __shared__ __align__(16) u16 Pl [64 * LSTR];
    __shared__ float ksumF[64];
    __shared__ float invdenL[64];

    #pragma unroll
    for (int r = 0; r < 2; ++r) {
        int idx = tid + r * 256;
        int i = idx >> 3, cg = (idx & 7) << 3;
        *(uint4*)&Qs [i*LSTR + cg] = *(const uint4*)&Qg [(size_t)(row0 + i) * 1024 + col + cg];
        *(uint4*)&Ks [i*LSTR + cg] = *(const uint4*)&Kg [(size_t)(row0 + i) * 1024 + col + cg];
        *(uint4*)&Sts[i*LSTR + cg] = *(const uint4*)&Stg[(size_t)blockIdx.x * 4096 + i * 64 + cg];
        uint4 vu = *(const uint4*)&Vg[(size_t)(row0 + i) * 1024 + col + cg];
        Vt[(cg+0)*LSTR + i] = (u16)(vu.x & 0xffff);
        Vt[(cg+1)*LSTR + i] = (u16)(vu.x >> 16);
        Vt[(cg+2)*LSTR + i] = (u16)(vu.y & 0xffff);
        Vt[(cg+3)*LSTR + i] = (u16)(vu.y >> 16);
        Vt[(cg+4)*LSTR + i] = (u16)(vu.z & 0xffff);
        Vt[(cg+5)*LSTR + i] = (u16)(vu.z >> 16);
        Vt[(cg+6)*LSTR + i] = (u16)(vu.w & 0xffff);
        Vt[(cg+7)*LSTR + i] = (u16)(vu.w >> 16);
    }
    if (tid < 64) ksumF[tid] = KSg[(size_t)blockIdx.x * 64 + tid];
    __syncthreads();

    const int li = l & 15;
    const int lg = l >> 4;
    const int i_row = w * 16 + li;

    short8v bq[2];
    #pragma unroll
    for (int kc = 0; kc < 2; ++kc)
        bq[kc] = *(const short8v*)&Qs[i_row * LSTR + lg*8 + kc*32];

    float den = EPSF;
    #pragma unroll
    for (int mj = 0; mj < 4; ++mj) {
        f32x4 sacc = (f32x4){0.f, 0.f, 0.f, 0.f};
        #pragma unroll
        for (int kc = 0; kc < 2; ++kc) {
            short8v ak = *(const short8v*)&Ks[(mj*16 + li) * LSTR + lg*8 + kc*32];
            sacc = __builtin_amdgcn_mfma_f32_16x16x32_bf16(ak, bq[kc], sacc, 0, 0, 0);
        }
        const int jbase = mj*16 + lg*4;
        float pv[4];
        #pragma unroll
        for (int r = 0; r < 4; ++r) {
            float v = sacc[r];
            v = (jbase + r <= i_row) ? v : 0.f;
            den += v;
            pv[r] = v;
        }
        u32 lo = (u32)f2bf(pv[0]) | ((u32)f2bf(pv[1]) << 16);
        u32 hi = (u32)f2bf(pv[2]) | ((u32)f2bf(pv[3]) << 16);
        *(uint2*)&Pl[i_row * LSTR + jbase] = make_uint2(lo, hi);
    }

    {
        const int d0 = lg * 16;
        uint4 q1 = *(const uint4*)&Qs[i_row * LSTR + d0];
        uint4 q2 = *(const uint4*)&Qs[i_row * LSTR + d0 + 8];
        den += bflo(q1.x)*ksumF[d0+0] + bfhi(q1.x)*ksumF[d0+1]
             + bflo(q1.y)*ksumF[d0+2] + bfhi(q1.y)*ksumF[d0+3]
             + bflo(q1.z)*ksumF[d0+4] + bfhi(q1.z)*ksumF[d0+5]
             + bflo(q1.w)*ksumF[d0+6] + bfhi(q1.w)*ksumF[d0+7]
             + bflo(q2.x)*ksumF[d0+8] + bfhi(q2.x)*ksumF[d0+9]
             + bflo(q2.y)*ksumF[d0+10]+ bfhi(q2.y)*ksumF[d0+11]
             + bflo(q2.z)*ksumF[d0+12]+ bfhi(q2.z)*ksumF[d0+13]
             + bflo(q2.w)*ksumF[d0+14]+ bfhi(q2.w)*ksumF[d0+15];
    }
    den += __shfl_xor(den, 16);
    den += __shfl_xor(den, 32);
    if (l < 16) invdenL[w*16 + l] = 1.f / den;

    f32x4 oacc[4];
    #pragma unroll
    for (int ne = 0; ne < 4; ++ne) oacc[ne] = (f32x4){0.f, 0.f, 0.f, 0.f};
    #pragma unroll
    for (int kc = 0; kc < 2; ++kc) {
        short8v ap = *(const short8v*)&Pl[i_row * LSTR + lg*8 + kc*32];
        short8v aq = bq[kc];
        #pragma unroll
        for (int ne = 0; ne < 4; ++ne) {
            short8v bv = *(const short8v*)&Vt [(ne*16 + li) * LSTR + lg*8 + kc*32];
            short8v bs = *(const short8v*)&Sts[(ne*16 + li) * LSTR + lg*8 + kc*32];
            oacc[ne] = __builtin_amdgcn_mfma_f32_16x16x32_bf16(ap, bv, oacc[ne], 0, 0, 0);
            oacc[ne] = __builtin_amdgcn_mfma_f32_16x16x32_bf16(aq, bs, oacc[ne], 0, 0, 0);
        }
    }

    float inv[4];
    #pragma unroll
    for (int r = 0; r < 4; ++r) inv[r] = invdenL[w*16 + lg*4 + r];
    #pragma unroll
    for (int ne = 0; ne < 4; ++ne)
        #pragma unroll
        for (int r = 0; r < 4; ++r)
            Pl[(w*16 + lg*4 + r) * LSTR + ne*16 + li] = f2bf(oacc[ne][r] * inv[r]);

    #pragma unroll
    for (int p = 0; p < 2; ++p) {
        int idx2 = l + p * 64;
        int ro = w*16 + (idx2 >> 3), cg = (idx2 & 7) << 3;
        *(uint4*)&AO[(size_t)(row0 + ro) * 1024 + col + cg] = *(const uint4*)&Pl[ro*LSTR + cg];
    }
}

extern "C" void kernel_launch(void* const* d_in, const int* in_sizes, int n_in,
                              void* d_out, int out_size, void* d_ws, size_t ws_size,
                              hipStream_t stream)
{
    const float* x  = (const float*)d_in[0];
    const float* Wq = (const float*)d_in[1];
    const float* Wk = (const float*)d_in[2];
    const float* Wv = (const float*)d_in[3];
    const float* Wo = (const float*)d_in[4];
    float* out = (float*)d_out;

    char* w = (char*)d_ws;
    u16*   QKVb = (u16*)(w);                        // 3 x 16777216 B = 50331648
    u16*   Qb   = QKVb;
    u16*   Kb   = QKVb + 8388608;
    u16*   Vb   = QKVb + 16777216;
    u16*   xb   = (u16*)(w + 50331648);             // 16777216 B (aliased AOb)
    u16*   AOb  = xb;
    u16*   Wcat = (u16*)(w + 67108864);             //  6291456 B
    u16*   Wob  = (u16*)(w + 73400320);             //  2097152 B
    u16*   CKVb = (u16*)(w + 75497472);             // 16777216 B (bf16, prefix in-place)
    float* CKS  = (float*)(w + 92274688);           //   524288 B -> end 92798976

    (void)hipFuncSetAttribute(reinterpret_cast<const void*>(k_gemm8),
                              hipFuncAttributeMaxDynamicSharedMemorySize, 131072);

    k_cast5    <<<6144, 256, 0, stream>>>(x, Wq, Wk, Wv, Wo, xb, Wcat, Wob);
    k_gemm8    <<<384,  512, 131072, stream>>>(xb, Wcat, QKVb);
    k_chunksums<<<2048, 256, 0, stream>>>(Kb, Vb, CKVb, CKS);
    k_prefix   <<<520,  256, 0, stream>>>(CKVb, CKS);
    k_attn2    <<<2048, 256, 0, stream>>>(Qb, Kb, Vb, CKVb, CKS, AOb);
    k_gemm7<8> <<<256,  256, 0, stream>>>(AOb, Wob, out);
}

// Round 9
// 144.370 us; speedup vs baseline: 1.0035x; 1.0035x over previous
//
#include <hip/hip_runtime.h>
#include <math.h>

// LinearAttention: B=2, S=4096, D=1024, H=16, Dh=64
// Round 9: k_gemm8 8-phase schedule, barriers fixed to match m201 template:
// raw __builtin_amdgcn_s_barrier() (NO memory clobber) + plain-volatile counted
// vmcnt waits. Stage map identical to r8 (correctness-proven). Everything else
// unchanged from r8.

#define EPSF 1e-8f

typedef unsigned short u16;
typedef unsigned int   u32;
typedef __attribute__((ext_vector_type(8))) short short8v;
typedef __attribute__((ext_vector_type(4))) float f32x4;

__device__ __forceinline__ float elu1(float x){ return x > 0.f ? x + 1.f : __expf(x); }
__device__ __forceinline__ u16 f2bf(float f){
    union{float f; u32 i;} c; c.f = f;
    u32 i = c.i + 0x7FFFu + ((c.i >> 16) & 1u);   // RNE
    return (u16)(i >> 16);
}
__device__ __forceinline__ float bf2f(u16 v){ union{u32 i; float f;} c; c.i = (u32)v << 16; return c.f; }
__device__ __forceinline__ float bflo(u32 v){ union{u32 i; float f;} c; c.i = v << 16; return c.f; }
__device__ __forceinline__ float bfhi(u32 v){ union{u32 i; float f;} c; c.i = v & 0xffff0000u; return c.f; }
__device__ __forceinline__ void f4a(float4 v, float* a){ a[0]=v.x; a[1]=v.y; a[2]=v.z; a[3]=v.w; }

__device__ __forceinline__ void gload16(const void* g, void* l){
    __builtin_amdgcn_global_load_lds((const __attribute__((address_space(1))) u32*)g,
                                     (__attribute__((address_space(3))) u32*)l, 16, 0, 0);
}

// ---------------- Kernel 0: cast fp32 -> bf16 ----------------
__global__ __launch_bounds__(256) void k_cast5(
    const float* __restrict__ x,  const float* __restrict__ wq,
    const float* __restrict__ wk, const float* __restrict__ wv,
    const float* __restrict__ wo,
    u16* __restrict__ xb, u16* __restrict__ wcat, u16* __restrict__ wob)
{
    size_t i8 = ((size_t)blockIdx.x * 256 + threadIdx.x) * 8;
    const float* s; u16* d; size_t off;
    if      (i8 <  8388608) { s = x;  d = xb;            off = i8; }
    else if (i8 <  9437184) { s = wq; d = wcat;          off = i8 - 8388608; }
    else if (i8 < 10485760) { s = wk; d = wcat + 1048576; off = i8 - 9437184; }
    else if (i8 < 11534336) { s = wv; d = wcat + 2097152; off = i8 - 10485760; }
    else                    { s = wo; d = wob;           off = i8 - 11534336; }
    float4 a = *(const float4*)&s[off];
    float4 b = *(const float4*)&s[off + 4];
    uint4 p;
    p.x = (u32)f2bf(a.x) | ((u32)f2bf(a.y) << 16);
    p.y = (u32)f2bf(a.z) | ((u32)f2bf(a.w) << 16);
    p.z = (u32)f2bf(b.x) | ((u32)f2bf(b.y) << 16);
    p.w = (u32)f2bf(b.z) | ((u32)f2bf(b.w) << 16);
    *(uint4*)&d[off] = p;
}

// ---------------- k_gemm8: 8-phase 256x256 fused QKV GEMM ----------------
// Same geometry/stage-map as r8 (correctness-proven). Barriers = raw builtin
// s_barrier (no clobber); vmcnt waits plain volatile, placed just before a
// barrier so LDS reads of the next phase cannot cross them.
#define R_A0 0
#define R_B0 32768
#define R_A1 65536
#define R_B1 98304

#define STG8(REG, SRC, T, KH) { \
    gload16((SRC) + (size_t)(T)*64 + (KH)*32,          dsm + (REG) + (KH)*16384 + wid*1024); \
    gload16((SRC) + 131072 + (size_t)(T)*64 + (KH)*32, dsm + (REG) + (KH)*16384 + 8192 + wid*1024); }

#define PHA8(REGA, REGB, KK, STCODE) { \
    _Pragma("unroll") for (int n = 0; n < 4; ++n) \
        bfr[n] = *(const short8v*)(dsm + (REGB) + (KK)*16384 + offB0 + n*1024); \
    _Pragma("unroll") for (int m = 0; m < 4; ++m) \
        afr[m] = *(const short8v*)(dsm + (REGA) + (KK)*16384 + offA0 + m*1024); \
    STCODE; \
    __builtin_amdgcn_s_barrier(); \
    __builtin_amdgcn_s_setprio(1); \
    _Pragma("unroll") for (int m = 0; m < 4; ++m) \
        _Pragma("unroll") for (int n = 0; n < 4; ++n) \
            acc[m][n] = __builtin_amdgcn_mfma_f32_16x16x32_bf16(afr[m], bfr[n], acc[m][n], 0, 0, 0); \
    __builtin_amdgcn_s_setprio(0); \
    __builtin_amdgcn_s_barrier(); }

#define PHB8(REGA, KK, STCODE, WCODE) { \
    _Pragma("unroll") for (int m = 0; m < 4; ++m) \
        afr[m] = *(const short8v*)(dsm + (REGA) + (KK)*16384 + 4096 + offA0 + m*1024); \
    STCODE; \
    __builtin_amdgcn_s_barrier(); \
    __builtin_amdgcn_s_setprio(1); \
    _Pragma("unroll") for (int m = 0; m < 4; ++m) \
        _Pragma("unroll") for (int n = 0; n < 4; ++n) \
            acc[4+m][n] = __builtin_amdgcn_mfma_f32_16x16x32_bf16(afr[m], bfr[n], acc[4+m][n], 0, 0, 0); \
    __builtin_amdgcn_s_setprio(0); \
    WCODE; \
    __builtin_amdgcn_s_barrier(); }

__global__ __launch_bounds__(512, 2) void k_gemm8(
    const u16* __restrict__ Ag, const u16* __restrict__ Wg, u16* __restrict__ C)
{
    extern __shared__ char dsm[];
    const int bid = blockIdx.x;
    const int nid = (bid & 7) * 48 + (bid >> 3);   // 384 = 8*48 bijective XCD swizzle
    const int bx  = nid / 12;                      // m-tile 0..31
    const int by  = nid % 12;                      // n-tile 0..11 (into 3072)
    const int m0  = bx * 256;
    const int n0  = by * 256;

    const int tid = threadIdx.x;
    const int l   = tid & 63;
    const int wid = tid >> 6;       // 0..7
    const int wm  = wid >> 2;       // 0..1
    const int wn  = wid & 3;        // 0..3
    const int li  = l & 15;
    const int kgi = l >> 4;

    const int ra0 = wm*128 + li;
    const int offA0 = ((ra0 >> 1) << 7) + (((((ra0 & 1) << 2) | kgi) ^ ((ra0 >> 1) & 7)) << 4);
    const int rb0 = wn*64 + li;
    const int offB0 = ((rb0 >> 1) << 7) + (((((rb0 & 1) << 2) | kgi) ^ ((rb0 >> 1) & 7)) << 4);

    const int sx   = (l & 7) ^ (l >> 3);
    const int rowb = 2*(wid*8 + (l >> 3)) + (sx >> 2);   // 0..127
    const int skg  = (sx & 3) * 8;
    const u16* srcA = Ag + (size_t)(m0 + rowb) * 1024 + skg;
    const u16* srcB = Wg + (size_t)(n0 + rowb) * 1024 + skg;

    f32x4 acc[8][4];
    #pragma unroll
    for (int m = 0; m < 8; ++m)
        #pragma unroll
        for (int n = 0; n < 4; ++n) acc[m][n] = (f32x4){0.f, 0.f, 0.f, 0.f};

    short8v afr[4], bfr[4];

    // prologue: t0 full (dbuf0) + t1.kh0 (dbuf1); vmcnt(4) -> t0 landed
    STG8(R_A0, srcA, 0, 0); STG8(R_B0, srcB, 0, 0);
    STG8(R_A0, srcA, 0, 1); STG8(R_B0, srcB, 0, 1);
    STG8(R_A1, srcA, 1, 0); STG8(R_B1, srcB, 1, 0);
    asm volatile("s_waitcnt vmcnt(4)");
    __builtin_amdgcn_s_barrier();

    #pragma unroll 1
    for (int j = 0; j < 7; ++j) {
        const int t = 2*j;
        PHA8(R_A0, R_B0, 0, { STG8(R_A1, srcA, t+1, 1) });
        PHB8(R_A0, 0,      { STG8(R_B1, srcB, t+1, 1) }, {});
        PHA8(R_A0, R_B0, 1, { STG8(R_A0, srcA, t+2, 0) });
        PHB8(R_A0, 1,      { STG8(R_B0, srcB, t+2, 0) },
             { asm volatile("s_waitcnt vmcnt(4)"); });
        PHA8(R_A1, R_B1, 0, { STG8(R_A0, srcA, t+2, 1) });
        PHB8(R_A1, 0,      { STG8(R_B0, srcB, t+2, 1) }, {});
        PHA8(R_A1, R_B1, 1, { STG8(R_A1, srcA, t+3, 0) });
        PHB8(R_A1, 1,      { STG8(R_B1, srcB, t+3, 0) },
             { asm volatile("s_waitcnt vmcnt(4)"); });
    }
    // peeled final iter (t=14): only t15.kh1 left to stage; vmcnt(0) once at ph4
    PHA8(R_A0, R_B0, 0, { STG8(R_A1, srcA, 15, 1) });
    PHB8(R_A0, 0,      { STG8(R_B1, srcB, 15, 1) }, {});
    PHA8(R_A0, R_B0, 1, {});
    PHB8(R_A0, 1, {},  { asm volatile("s_waitcnt vmcnt(0)"); });
    PHA8(R_A1, R_B1, 0, {});
    PHB8(R_A1, 0, {}, {});
    PHA8(R_A1, R_B1, 1, {});
    PHB8(R_A1, 1, {}, {});

    // epilogue. C/D layout: col = lane&15, row = (lane>>4)*4 + reg
    const int matrix = by >> 2;                 // 0:Q 1:K 2:V
    const bool do_elu = matrix < 2;
    u16* outp = C + (size_t)matrix * 8388608;
    const int r0 = m0 + wm*128 + kgi*4;
    const int c0 = (by & 3)*256 + wn*64 + li;
    #pragma unroll
    for (int m = 0; m < 8; ++m)
        #pragma unroll
        for (int n = 0; n < 4; ++n)
            #pragma unroll
            for (int r = 0; r < 4; ++r) {
                float v = acc[m][n][r];
                if (do_elu) v = elu1(v);
                outp[(size_t)(r0 + m*16 + r) * 1024 + c0 + n*16] = f2bf(v);
            }
}

// ---------------- k_gemm7 (r6): out GEMM (f32 out), 3-buffer ring + counted vmcnt ----------------
template<int NBY>
__global__ __launch_bounds__(256, 2) void k_gemm7(
    const u16* __restrict__ Ag, const u16* __restrict__ Wg, float* __restrict__ Cv)
{
    __shared__ __align__(16) char dsm[73728];
    const int bid = blockIdx.x;
    const int nid = (bid & 7) * ((32 * NBY) >> 3) + (bid >> 3);
    const int bx  = nid / NBY;
    const int by  = nid % NBY;
    const int m0  = bx * 256;
    const int n0  = by * 128;

    const int tid = threadIdx.x;
    const int l   = tid & 63;
    const int wid = tid >> 6;
    const int wm  = wid >> 1;
    const int wn  = wid & 1;
    const int li  = l & 15;
    const int kgi = l >> 4;

    const int ra0 = wm*128 + li;
    const int offA0 = (ra0 >> 1)*128 + (((((ra0 & 1) << 2) | kgi) ^ ((ra0 >> 1) & 7)) << 4);
    const int rb0 = wn*64 + li;
    const int offB0 = (rb0 >> 1)*128 + (((((rb0 & 1) << 2) | kgi) ^ ((rb0 >> 1) & 7)) << 4);

    const int sx   = (l & 7) ^ (l >> 3);
    const int rowb = 2*(wid*8 + (l >> 3)) + (sx >> 2);
    const int skg  = (sx & 3) * 8;
    const u16* srcA = Ag + (size_t)(m0 + rowb) * 1024 + skg;
    const u16* srcB = Wg + (size_t)(n0 + rowb) * 1024 + skg;

    f32x4 acc[8][4];
    #pragma unroll
    for (int m = 0; m < 8; ++m)
        #pragma unroll
        for (int n = 0; n < 4; ++n) acc[m][n] = (f32x4){0.f, 0.f, 0.f, 0.f};

    #define ST7(BUF, T) { \
        char* ab = dsm + (BUF)*24576; \
        char* bb = ab + 16384; \
        _Pragma("unroll") for (int j = 0; j < 4; ++j) \
            gload16(srcA + (size_t)j*65536 + (T)*32, ab + j*4096 + wid*1024); \
        _Pragma("unroll") for (int j = 0; j < 2; ++j) \
            gload16(srcB + (size_t)j*65536 + (T)*32, bb + j*4096 + wid*1024); }

    #define CP7(BUF) { \
        const char* Ab = dsm + (BUF)*24576; \
        const char* Bb = Ab + 16384; \
        short8v bfr[4]; \
        _Pragma("unroll") for (int n = 0; n < 4; ++n) bfr[n] = *(const short8v*)(Bb + offB0 + n*1024); \
        __builtin_amdgcn_s_setprio(1); \
        _Pragma("unroll") for (int m = 0; m < 8; ++m) { \
            short8v afr = *(const short8v*)(Ab + offA0 + m*1024); \
            _Pragma("unroll") for (int n = 0; n < 4; ++n) \
                acc[m][n] = __builtin_amdgcn_mfma_f32_16x16x32_bf16(afr, bfr[n], acc[m][n], 0, 0, 0); \
        } \
        __builtin_amdgcn_s_setprio(0); }

    #define STEP7(CUR, STB, TS) { \
        ST7(STB, TS); \
        CP7(CUR); \
        asm volatile("s_waitcnt vmcnt(6)"); \
        __builtin_amdgcn_s_barrier(); }

    ST7(0, 0); ST7(1, 1);
    asm volatile("s_waitcnt vmcnt(6)");
    __builtin_amdgcn_s_barrier();

    #pragma unroll 1
    for (int g = 0; g < 10; ++g) {
        const int t = g * 3;
        STEP7(0, 2, t + 2);
        STEP7(1, 0, t + 3);
        STEP7(2, 1, t + 4);
    }
    CP7(0);
    asm volatile("s_waitcnt vmcnt(0)");
    __builtin_amdgcn_s_barrier();
    CP7(1);
    #undef STEP7
    #undef CP7
    #undef ST7

    const int r0 = m0 + wm*128 + kgi*4;
    const int c0 = by*128 + wn*64 + li;
    #pragma unroll
    for (int m = 0; m < 8; ++m)
        #pragma unroll
        for (int n = 0; n < 4; ++n)
            #pragma unroll
            for (int r = 0; r < 4; ++r)
                Cv[(size_t)(r0 + m*16 + r) * 1024 + c0 + n*16] = acc[m][n][r];
}

// ---------------- per-chunk KV sums (bf16 in, bf16 out [e][d], fp32 accum) ----------------
__global__ __launch_bounds__(256) void k_chunksums(
    const u16* __restrict__ Kg, const u16* __restrict__ Vg,
    u16* __restrict__ CKVb, float* __restrict__ CKS)
{
    const int tid = threadIdx.x;
    const int tx = tid & 15, ty = tid >> 4;
    const int c  = blockIdx.x & 63;
    const int bh = blockIdx.x >> 6;
    const int b = bh >> 4, h = bh & 15;
    const int row0 = b * 4096 + c * 64;
    const int col  = h * 64;

    __shared__ float Ks[64][68];
    __shared__ float Vs[64][68];

    #pragma unroll
    for (int r = 0; r < 2; ++r) {
        int idx = tid + r * 256;
        int i = idx >> 3, cg = (idx & 7) << 3;
        uint4 ku = *(const uint4*)&Kg[(size_t)(row0 + i) * 1024 + col + cg];
        uint4 vu = *(const uint4*)&Vg[(size_t)(row0 + i) * 1024 + col + cg];
        Ks[i][cg+0]=bflo(ku.x); Ks[i][cg+1]=bfhi(ku.x);
        Ks[i][cg+2]=bflo(ku.y); Ks[i][cg+3]=bfhi(ku.y);
        Ks[i][cg+4]=bflo(ku.z); Ks[i][cg+5]=bfhi(ku.z);
        Ks[i][cg+6]=bflo(ku.w); Ks[i][cg+7]=bfhi(ku.w);
        Vs[i][cg+0]=bflo(vu.x); Vs[i][cg+1]=bfhi(vu.x);
        Vs[i][cg+2]=bflo(vu.y); Vs[i][cg+3]=bfhi(vu.y);
        Vs[i][cg+4]=bflo(vu.z); Vs[i][cg+5]=bfhi(vu.z);
        Vs[i][cg+6]=bflo(vu.w); Vs[i][cg+7]=bfhi(vu.w);
    }
    __syncthreads();

    float acc[4][4] = {};
    #pragma unroll 8
    for (int i = 0; i < 64; ++i) {
        float kv[4], vv[4];
        f4a(*(const float4*)&Ks[i][ty*4], kv);
        f4a(*(const float4*)&Vs[i][tx*4], vv);
        #pragma unroll
        for (int a = 0; a < 4; ++a)
            #pragma unroll
            for (int e = 0; e < 4; ++e)
                acc[a][e] = fmaf(kv[a], vv[e], acc[a][e]);
    }
    u16* ckv = &CKVb[(size_t)blockIdx.x * 4096];
    #pragma unroll
    for (int e = 0; e < 4; ++e) {
        u32 p0 = (u32)f2bf(acc[0][e]) | ((u32)f2bf(acc[1][e]) << 16);
        u32 p1 = (u32)f2bf(acc[2][e]) | ((u32)f2bf(acc[3][e]) << 16);
        *(uint2*)&ckv[(tx*4 + e) * 64 + ty*4] = make_uint2(p0, p1);
    }

    if (tid < 64) {
        float s = 0.f;
        #pragma unroll 8
        for (int i = 0; i < 64; ++i) s += Ks[i][tid];
        CKS[(size_t)blockIdx.x * 64 + tid] = s;
    }
}

// ---------------- exclusive prefix over chunks (CKV bf16 in-place + CKS fused) ----------------
__global__ __launch_bounds__(256) void k_prefix(u16* __restrict__ CKV, float* __restrict__ CKS)
{
    if (blockIdx.x < 512) {
        const int bh = blockIdx.x >> 4;
        const int p  = ((blockIdx.x & 15) << 8) + threadIdx.x;
        const size_t base = (size_t)bh * 64 * 4096 + p;
        float acc = 0.f;
        #pragma unroll
        for (int c = 0; c < 64; ++c) {
            float t = bf2f(CKV[base + (size_t)c * 4096]);
            CKV[base + (size_t)c * 4096] = f2bf(acc);
            acc += t;
        }
    } else {
        const int idx = (blockIdx.x - 512) * 256 + threadIdx.x;
        const int bh = idx >> 6, d = idx & 63;
        const size_t base = (size_t)bh * 64 * 64 + d;
        float v[64];
        #pragma unroll
        for (int c = 0; c < 64; ++c) v[c] = CKS[base + (size_t)c * 64];
        float acc = 0.f;
        #pragma unroll
        for (int c = 0; c < 64; ++c) { float t = v[c]; CKS[base + (size_t)c * 64] = acc; acc += t; }
    }
}

// ---------------- MFMA per-chunk attention ----------------
#define LSTR 72
__global__ __launch_bounds__(256) void k_attn2(
    const u16* __restrict__ Qg, const u16* __restrict__ Kg, const u16* __restrict__ Vg,
    const u16* __restrict__ Stg, const float* __restrict__ KSg, u16* __restrict__ AO)
{
    const int tid = threadIdx.x;
    const int l = tid & 63;
    const int w = tid >> 6;
    const int c  = blockIdx.x & 63;
    const int bh = blockIdx.x >> 6;
    const int row0 = (bh >> 4) * 4096 + c * 64;
    const int col  = (bh & 15) * 64;

    __shared__ __align__(16) u16 Qs [64 * LSTR];
    __shared__ __align__(16) u16 Ks [64 * LSTR];
    __shared__ __align__(16) u16 Vt [64 * LSTR];
    __shared__ __align__(16) u16 Sts[64 * LSTR];
    __shared__ __align__(16) u16 Pl [64 * LSTR];
    __shared__ float ksumF[64];
    __shared__ float invdenL[64];

    #pragma unroll
    for (int r = 0; r < 2; ++r) {
        int idx = tid + r * 256;
        int i = idx >> 3, cg = (idx & 7) << 3;
        *(uint4*)&Qs [i*LSTR + cg] = *(const uint4*)&Qg [(size_t)(row0 + i) * 1024 + col + cg];
        *(uint4*)&Ks [i*LSTR + cg] = *(const uint4*)&Kg [(size_t)(row0 + i) * 1024 + col + cg];
        *(uint4*)&Sts[i*LSTR + cg] = *(const uint4*)&Stg[(size_t)blockIdx.x * 4096 + i * 64 + cg];
        uint4 vu = *(const uint4*)&Vg[(size_t)(row0 + i) * 1024 + col + cg];
        Vt[(cg+0)*LSTR + i] = (u16)(vu.x & 0xffff);
        Vt[(cg+1)*LSTR + i] = (u16)(vu.x >> 16);
        Vt[(cg+2)*LSTR + i] = (u16)(vu.y & 0xffff);
        Vt[(cg+3)*LSTR + i] = (u16)(vu.y >> 16);
        Vt[(cg+4)*LSTR + i] = (u16)(vu.z & 0xffff);
        Vt[(cg+5)*LSTR + i] = (u16)(vu.z >> 16);
        Vt[(cg+6)*LSTR + i] = (u16)(vu.w & 0xffff);
        Vt[(cg+7)*LSTR + i] = (u16)(vu.w >> 16);
    }
    if (tid < 64) ksumF[tid] = KSg[(size_t)blockIdx.x * 64 + tid];
    __syncthreads();

    const int li = l & 15;
    const int lg = l >> 4;
    const int i_row = w * 16 + li;

    short8v bq[2];
    #pragma unroll
    for (int kc = 0; kc < 2; ++kc)
        bq[kc] = *(const short8v*)&Qs[i_row * LSTR + lg*8 + kc*32];

    float den = EPSF;
    #pragma unroll
    for (int mj = 0; mj < 4; ++mj) {
        f32x4 sacc = (f32x4){0.f, 0.f, 0.f, 0.f};
        #pragma unroll
        for (int kc = 0; kc < 2; ++kc) {
            short8v ak = *(const short8v*)&Ks[(mj*16 + li) * LSTR + lg*8 + kc*32];
            sacc = __builtin_amdgcn_mfma_f32_16x16x32_bf16(ak, bq[kc], sacc, 0, 0, 0);
        }
        const int jbase = mj*16 + lg*4;
        float pv[4];
        #pragma unroll
        for (int r = 0; r < 4; ++r) {
            float v = sacc[r];
            v = (jbase + r <= i_row) ? v : 0.f;
            den += v;
            pv[r] = v;
        }
        u32 lo = (u32)f2bf(pv[0]) | ((u32)f2bf(pv[1]) << 16);
        u32 hi = (u32)f2bf(pv[2]) | ((u32)f2bf(pv[3]) << 16);
        *(uint2*)&Pl[i_row * LSTR + jbase] = make_uint2(lo, hi);
    }

    {
        const int d0 = lg * 16;
        uint4 q1 = *(const uint4*)&Qs[i_row * LSTR + d0];
        uint4 q2 = *(const uint4*)&Qs[i_row * LSTR + d0 + 8];
        den += bflo(q1.x)*ksumF[d0+0] + bfhi(q1.x)*ksumF[d0+1]
             + bflo(q1.y)*ksumF[d0+2] + bfhi(q1.y)*ksumF[d0+3]
             + bflo(q1.z)*ksumF[d0+4] + bfhi(q1.z)*ksumF[d0+5]
             + bflo(q1.w)*ksumF[d0+6] + bfhi(q1.w)*ksumF[d0+7]
             + bflo(q2.x)*ksumF[d0+8] + bfhi(q2.x)*ksumF[d0+9]
             + bflo(q2.y)*ksumF[d0+10]+ bfhi(q2.y)*ksumF[d0+11]
             + bflo(q2.z)*ksumF[d0+12]+ bfhi(q2.z)*ksumF[d0+13]
             + bflo(q2.w)*ksumF[d0+14]+ bfhi(q2.w)*ksumF[d0+15];
    }
    den += __shfl_xor(den, 16);
    den += __shfl_xor(den, 32);
    if (l < 16) invdenL[w*16 + l] = 1.f / den;

    f32x4 oacc[4];
    #pragma unroll
    for (int ne = 0; ne < 4; ++ne) oacc[ne] = (f32x4){0.f, 0.f, 0.f, 0.f};
    #pragma unroll
    for (int kc = 0; kc < 2; ++kc) {
        short8v ap = *(const short8v*)&Pl[i_row * LSTR + lg*8 + kc*32];
        short8v aq = bq[kc];
        #pragma unroll
        for (int ne = 0; ne < 4; ++ne) {
            short8v bv = *(const short8v*)&Vt [(ne*16 + li) * LSTR + lg*8 + kc*32];
            short8v bs = *(const short8v*)&Sts[(ne*16 + li) * LSTR + lg*8 + kc*32];
            oacc[ne] = __builtin_amdgcn_mfma_f32_16x16x32_bf16(ap, bv, oacc[ne], 0, 0, 0);
            oacc[ne] = __builtin_amdgcn_mfma_f32_16x16x32_bf16(aq, bs, oacc[ne], 0, 0, 0);
        }
    }

    float inv[4];
    #pragma unroll
    for (int r = 0; r < 4; ++r) inv[r] = invdenL[w*16 + lg*4 + r];
    #pragma unroll
    for (int ne = 0; ne < 4; ++ne)
        #pragma unroll
        for (int r = 0; r < 4; ++r)
            Pl[(w*16 + lg*4 + r) * LSTR + ne*16 + li] = f2bf(oacc[ne][r] * inv[r]);

    #pragma unroll
    for (int p = 0; p < 2; ++p) {
        int idx2 = l + p * 64;
        int ro = w*16 + (idx2 >> 3), cg = (idx2 & 7) << 3;
        *(uint4*)&AO[(size_t)(row0 + ro) * 1024 + col + cg] = *(const uint4*)&Pl[ro*LSTR + cg];
    }
}

extern "C" void kernel_launch(void* const* d_in, const int* in_sizes, int n_in,
                              void* d_out, int out_size, void* d_ws, size_t ws_size,
                              hipStream_t stream)
{
    const float* x  = (const float*)d_in[0];
    const float* Wq = (const float*)d_in[1];
    const float* Wk = (const float*)d_in[2];
    const float* Wv = (const float*)d_in[3];
    const float* Wo = (const float*)d_in[4];
    float* out = (float*)d_out;

    char* w = (char*)d_ws;
    u16*   QKVb = (u16*)(w);                        // 3 x 16777216 B = 50331648
    u16*   Qb   = QKVb;
    u16*   Kb   = QKVb + 8388608;
    u16*   Vb   = QKVb + 16777216;
    u16*   xb   = (u16*)(w + 50331648);             // 16777216 B (aliased AOb)
    u16*   AOb  = xb;
    u16*   Wcat = (u16*)(w + 67108864);             //  6291456 B
    u16*   Wob  = (u16*)(w + 73400320);             //  2097152 B
    u16*   CKVb = (u16*)(w + 75497472);             // 16777216 B (bf16, prefix in-place)
    float* CKS  = (float*)(w + 92274688);           //   524288 B -> end 92798976

    (void)hipFuncSetAttribute(reinterpret_cast<const void*>(k_gemm8),
                              hipFuncAttributeMaxDynamicSharedMemorySize, 131072);

    k_cast5    <<<6144, 256, 0, stream>>>(x, Wq, Wk, Wv, Wo, xb, Wcat, Wob);
    k_gemm8    <<<384,  512, 131072, stream>>>(xb, Wcat, QKVb);
    k_chunksums<<<2048, 256, 0, stream>>>(Kb, Vb, CKVb, CKS);
    k_prefix   <<<520,  256, 0, stream>>>(CKVb, CKS);
    k_attn2    <<<2048, 256, 0, stream>>>(Qb, Kb, Vb, CKVb, CKS, AOb);
    k_gemm7<8> <<<256,  256, 0, stream>>>(AOb, Wob, out);
}